// Round 8
// baseline (215.798 us; speedup 1.0000x reference)
//
#include <hip/hip_runtime.h>

// ------- MFMA fp16 LSTM, skewed-layer pipeline, parity-unrolled phases -------
// Phase p computes layer1(t=p) AND layer0(t=p+1) between barriers (29 barriers).
// Round 8: SINGLE CHANGE vs round 7 — __launch_bounds__(512) +
// amdgpu_waves_per_eu(4,4). Rounds 3/4/5/7 (min-waves=4) all pinned VGPR=64 and
// spilled the A-weight fragments (WRITE_SIZE 23-28 MB vs 0.64 MB output);
// round 6 (min-waves=2) was spill-free (VGPR 80, WRITE 0.64 MB) but halved
// residency. Pinning waves/EU to exactly 4 gives the allocator a 128-reg
// budget with no occupancy incentive to spill: spill-free at 16 waves/CU.
//
// GEMM: C[m=gate(256)][n=batch(32)] = W[m][k] * data[k][n], gate rows permuted
// row'=4*unit+gate so a lane's 4 C-regs = (i,f,g,o) of one unit; c-state in VGPRs.
// Block = 512 thr (8 waves), wave w owns m-tiles {2w,2w+1} x n-tiles {0,1}.
// A (weights) gathered once per block from global fp32 (L2-resident).
// bias0 folded as k=28 constant-1 column; bias1 pre-added into acc init.
// B in LDS frag-linear layout: lane reads 16B at lane*16, conflict-free b128.
// Planes (flat arrays, plane P at P*size): h0(t)->h0p[t&1], h1(t)->h1p[t&1],
// x(t)->xb[t&1].

typedef _Float16 half8 __attribute__((ext_vector_type(8)));
typedef float floatx4 __attribute__((ext_vector_type(4)));

// Breadth-first 4-tile gate batch: acc -> (c update, h write into plane).
__device__ __forceinline__ void gate_batch4(const floatx4 (&acc)[2][2], float (&c)[4],
                                            _Float16* __restrict__ plane,
                                            const int (&hwr)[2][2]) {
    float ei[4], ef[4], eg[4], eo[4];
    #pragma unroll
    for (int tt = 0; tt < 4; ++tt) {
        floatx4 a = acc[tt >> 1][tt & 1];
        ei[tt] = __expf(-a[0]);
        ef[tt] = __expf(-a[1]);
        eg[tt] = __expf(2.0f * a[2]);
        eo[tt] = __expf(-a[3]);
    }
    float ri[4], rf[4], rg[4], ro[4];
    #pragma unroll
    for (int tt = 0; tt < 4; ++tt) {
        ri[tt] = __builtin_amdgcn_rcpf(1.0f + ei[tt]);
        rf[tt] = __builtin_amdgcn_rcpf(1.0f + ef[tt]);
        rg[tt] = __builtin_amdgcn_rcpf(1.0f + eg[tt]);
        ro[tt] = __builtin_amdgcn_rcpf(1.0f + eo[tt]);
    }
    float ec[4];
    #pragma unroll
    for (int tt = 0; tt < 4; ++tt) {
        float tg = 1.0f - 2.0f * rg[tt];
        float cn = rf[tt] * c[tt] + ri[tt] * tg;
        c[tt] = cn;
        ec[tt] = __expf(2.0f * cn);
    }
    #pragma unroll
    for (int tt = 0; tt < 4; ++tt) {
        float tc = 1.0f - 2.0f * __builtin_amdgcn_rcpf(ec[tt] + 1.0f);
        plane[hwr[tt >> 1][tt & 1]] = (_Float16)(ro[tt] * tc);
    }
}

// One interior phase with compile-time parity PR (p & 1 == PR):
//   reads  h0(p)=h0p[PR], h1(p-1)=h1p[PR^1], x(p+1)=xb[PR^1]
//   writes h0(p+1)=h0p[PR^1], h1(p)=h1p[PR], stages x(p+2)->xb[PR]
template <int PR>
__device__ __forceinline__ void interior_phase(
        int xoff, const float* const (&xg)[2], bool xvalid, int xi, const int (&xstg)[2],
        const half8 (&A0)[2][3], const half8 (&A1)[2][4], const floatx4 (&bias1)[2],
        float (&c0)[4], float (&c1)[4],
        const int (&xrd)[2], const int (&hrd)[2][2], const int (&hwr)[2][2],
        _Float16* __restrict__ h0p, _Float16* __restrict__ h1p, _Float16* __restrict__ xb) {
    constexpr int H0R = PR * 2048, H0W = (PR ^ 1) * 2048;
    constexpr int H1R = (PR ^ 1) * 2048, H1W = PR * 2048;
    constexpr int XR = (PR ^ 1) * 1024, XW = PR * 1024;

    // global prefetch x(p+2) first (latency hidden under MFMA/gate section)
    float xn[2] = {0.f, 0.f};
    #pragma unroll
    for (int s = 0; s < 2; ++s)
        if (xvalid) xn[s] = xg[s][xoff];

    // B-fragment loads: bx + bh0 (shared by both GEMMs)
    half8 bx[2], bh0[2][2];
    #pragma unroll
    for (int in = 0; in < 2; ++in) {
        bx[in] = *(const half8*)&xb[XR + xrd[in]];
        #pragma unroll
        for (int kt = 0; kt < 2; ++kt)
            bh0[kt][in] = *(const half8*)&h0p[H0R + hrd[kt][in]];
    }

    floatx4 acc0[2][2], acc1[2][2];
    #pragma unroll
    for (int im = 0; im < 2; ++im)
        #pragma unroll
        for (int in = 0; in < 2; ++in) {
            acc0[im][in] = (floatx4){0.f, 0.f, 0.f, 0.f};
            acc1[im][in] = bias1[im];
        }
    #pragma unroll
    for (int in = 0; in < 2; ++in)
        #pragma unroll
        for (int im = 0; im < 2; ++im)
            acc0[im][in] = __builtin_amdgcn_mfma_f32_16x16x32_f16(A0[im][0], bx[in], acc0[im][in], 0, 0, 0);
    #pragma unroll
    for (int kt = 0; kt < 2; ++kt)
        #pragma unroll
        for (int in = 0; in < 2; ++in)
            #pragma unroll
            for (int im = 0; im < 2; ++im) {
                acc0[im][in] = __builtin_amdgcn_mfma_f32_16x16x32_f16(A0[im][kt + 1], bh0[kt][in], acc0[im][in], 0, 0, 0);
                acc1[im][in] = __builtin_amdgcn_mfma_f32_16x16x32_f16(A1[im][kt],     bh0[kt][in], acc1[im][in], 0, 0, 0);
            }
    // bh1 loaded late (short liveness -> lower register pressure)
    half8 bh1[2][2];
    #pragma unroll
    for (int kt = 0; kt < 2; ++kt)
        #pragma unroll
        for (int in = 0; in < 2; ++in)
            bh1[kt][in] = *(const half8*)&h1p[H1R + hrd[kt][in]];
    #pragma unroll
    for (int kt = 0; kt < 2; ++kt)
        #pragma unroll
        for (int in = 0; in < 2; ++in)
            #pragma unroll
            for (int im = 0; im < 2; ++im)
                acc1[im][in] = __builtin_amdgcn_mfma_f32_16x16x32_f16(A1[im][kt + 2], bh1[kt][in], acc1[im][in], 0, 0, 0);

    gate_batch4(acc0, c0, &h0p[H0W], hwr);   // h0(p+1)
    gate_batch4(acc1, c1, &h1p[H1W], hwr);   // h1(p)

    #pragma unroll
    for (int s = 0; s < 2; ++s)
        xb[XW + xstg[s]] = (xi == 28) ? (_Float16)1.0f : (_Float16)xn[s];
    __syncthreads();
}

__launch_bounds__(512)
__attribute__((amdgpu_waves_per_eu(4, 4)))
__global__ void lstm_mfma(const float* __restrict__ x,
                          const float* __restrict__ Wih0, const float* __restrict__ Whh0,
                          const float* __restrict__ bih0, const float* __restrict__ bhh0,
                          const float* __restrict__ Wih1, const float* __restrict__ Whh1,
                          const float* __restrict__ bih1, const float* __restrict__ bhh1,
                          const float* __restrict__ Wlin, const float* __restrict__ blin,
                          float* __restrict__ out) {
    __shared__ __align__(16) _Float16 h0p[2 * 2048];
    __shared__ __align__(16) _Float16 h1p[2 * 2048];
    __shared__ __align__(16) _Float16 xb[2 * 1024];
    __shared__ float wlin_s[640];
    __shared__ float blin_s[10];

    const int lane = threadIdx.x;
    const int w    = threadIdx.y;          // 0..7
    const int tid  = w * 64 + lane;        // 0..511
    const int quad = lane >> 4;
    const int col  = lane & 15;

    // ---- gather A fragments from global fp32 weights (one-time; L2-resident) ----
    half8 A0[2][3], A1[2][4];
    #pragma unroll
    for (int im = 0; im < 2; ++im) {
        int mt = 2 * w + im;
        int m  = mt * 16 + col;
        int u  = m >> 2, g = m & 3;
        int row = g * 64 + u;                       // original weight row
        #pragma unroll
        for (int kt = 0; kt < 3; ++kt) {
            half8 r;
            #pragma unroll
            for (int j = 0; j < 8; ++j) {
                int k = kt * 32 + quad * 8 + j;
                float v;
                if (k < 28)       v = Wih0[row * 28 + k];
                else if (k == 28) v = bih0[row] + bhh0[row];
                else if (k < 32)  v = 0.f;
                else              v = Whh0[row * 64 + (k - 32)];
                r[j] = (_Float16)v;
            }
            A0[im][kt] = r;
        }
        #pragma unroll
        for (int kt = 0; kt < 4; ++kt) {
            half8 r;
            #pragma unroll
            for (int j = 0; j < 8; ++j) {
                int k = kt * 32 + quad * 8 + j;
                float v = (k < 64) ? Wih1[row * 64 + k] : Whh1[row * 64 + (k - 64)];
                r[j] = (_Float16)v;
            }
            A1[im][kt] = r;
        }
    }
    floatx4 bias1[2];
    #pragma unroll
    for (int im = 0; im < 2; ++im) {
        int u = (2 * w + im) * 4 + quad;
        #pragma unroll
        for (int r = 0; r < 4; ++r) bias1[im][r] = bih1[r * 64 + u] + bhh1[r * 64 + u];
    }

    // ---- t-invariant LDS offsets (halves) ----
    int xrd[2], hrd[2][2], hwr[2][2];
    #pragma unroll
    for (int in = 0; in < 2; ++in) {
        xrd[in] = in * 512 + lane * 8;
        #pragma unroll
        for (int kt = 0; kt < 2; ++kt) hrd[kt][in] = (in * 2 + kt) * 512 + lane * 8;
        #pragma unroll
        for (int im = 0; im < 2; ++im) {
            int u = (2 * w + im) * 4 + quad;
            hwr[im][in] = (in * 2 + (u >> 5)) * 512 + (((u >> 3) & 3) * 16 + col) * 8 + (u & 7);
        }
    }

    // ---- x prefetch: slot s covers b=(tid>>5)+16s, i=tid&31 ----
    const int xi = tid & 31;
    const bool xvalid = xi < 28;
    const float* xg[2];
    int xstg[2];
    #pragma unroll
    for (int s = 0; s < 2; ++s) {
        int b = (tid >> 5) + s * 16;
        xg[s]   = x + (blockIdx.x * 32 + b) * 784 + xi;
        xstg[s] = (b >> 4) * 512 + ((xi >> 3) * 16 + (b & 15)) * 8 + (xi & 7);
    }

    // ---- init: zero h0(-1)=h0p[1], h1(-1)=h1p[1]; stage x(0) into xb[0] ----
    {
        int* z0 = (int*)&h0p[2048];
        int* z1 = (int*)&h1p[2048];
        #pragma unroll
        for (int i = tid; i < 1024; i += 512) { z0[i] = 0; z1[i] = 0; }
        #pragma unroll
        for (int s = 0; s < 2; ++s) {
            float xv = xvalid ? xg[s][0] : 0.f;
            xb[xstg[s]] = (xi == 28) ? (_Float16)1.0f : (_Float16)xv;
        }
    }
    __syncthreads();

    float c0[4] = {0.f, 0.f, 0.f, 0.f};
    float c1[4] = {0.f, 0.f, 0.f, 0.f};

    // ======== prologue phase (p = -1): layer0(t=0) only ========
    {
        float xn[2] = {0.f, 0.f};
        #pragma unroll
        for (int s = 0; s < 2; ++s)
            if (xvalid) xn[s] = xg[s][28];          // x(1)

        floatx4 acc0[2][2];
        #pragma unroll
        for (int im = 0; im < 2; ++im)
            #pragma unroll
            for (int in = 0; in < 2; ++in)
                acc0[im][in] = (floatx4){0.f, 0.f, 0.f, 0.f};
        #pragma unroll
        for (int in = 0; in < 2; ++in) {
            half8 bf = *(const half8*)&xb[xrd[in]];
            #pragma unroll
            for (int im = 0; im < 2; ++im)
                acc0[im][in] = __builtin_amdgcn_mfma_f32_16x16x32_f16(A0[im][0], bf, acc0[im][in], 0, 0, 0);
        }
        #pragma unroll
        for (int kt = 0; kt < 2; ++kt) {
            #pragma unroll
            for (int in = 0; in < 2; ++in) {
                half8 bf = *(const half8*)&h0p[2048 + hrd[kt][in]];   // zeros
                #pragma unroll
                for (int im = 0; im < 2; ++im)
                    acc0[im][in] = __builtin_amdgcn_mfma_f32_16x16x32_f16(A0[im][kt + 1], bf, acc0[im][in], 0, 0, 0);
            }
        }
        gate_batch4(acc0, c0, &h0p[0], hwr);        // h0(0) -> plane 0
        #pragma unroll
        for (int s = 0; s < 2; ++s)                 // stage x(1) -> plane 1
            xb[1024 + xstg[s]] = (xi == 28) ? (_Float16)1.0f : (_Float16)xn[s];
        __syncthreads();
    }

    // ======== main phases p = 0..25 (13 parity-unrolled pairs) ========
    int xoff = 2 * 28;                              // x(p+2) index for p=0
    #pragma unroll 1
    for (int pp = 0; pp < 13; ++pp) {
        interior_phase<0>(xoff,      xg, xvalid, xi, xstg, A0, A1, bias1, c0, c1,
                          xrd, hrd, hwr, h0p, h1p, xb);
        interior_phase<1>(xoff + 28, xg, xvalid, xi, xstg, A0, A1, bias1, c0, c1,
                          xrd, hrd, hwr, h0p, h1p, xb);
        xoff += 56;
    }
    // ---- phase p = 26 (parity 0), x prefetch clamped to x(27) (re-stage, harmless) ----
    interior_phase<0>(27 * 28, xg, xvalid, xi, xstg, A0, A1, bias1, c0, c1,
                      xrd, hrd, hwr, h0p, h1p, xb);

    // ======== final phase (p = 27, parity 1): layer1(t=27) only ========
    {
        floatx4 acc1[2][2];
        #pragma unroll
        for (int im = 0; im < 2; ++im)
            #pragma unroll
            for (int in = 0; in < 2; ++in)
                acc1[im][in] = bias1[im];
        #pragma unroll
        for (int kt = 0; kt < 2; ++kt) {
            #pragma unroll
            for (int in = 0; in < 2; ++in) {
                half8 b0 = *(const half8*)&h0p[2048 + hrd[kt][in]];   // h0(27)
                half8 b1 = *(const half8*)&h1p[hrd[kt][in]];          // h1(26)
                #pragma unroll
                for (int im = 0; im < 2; ++im) {
                    acc1[im][in] = __builtin_amdgcn_mfma_f32_16x16x32_f16(A1[im][kt],     b0, acc1[im][in], 0, 0, 0);
                    acc1[im][in] = __builtin_amdgcn_mfma_f32_16x16x32_f16(A1[im][kt + 2], b1, acc1[im][in], 0, 0, 0);
                }
            }
        }
        gate_batch4(acc1, c1, &h1p[2048], hwr);     // h1(27) -> plane 1
        __syncthreads();
    }

    // ---- epilogue: out = h1(27) @ Wlin^T + blin   (h1(27) in plane 1) ----
    #pragma unroll
    for (int i = tid; i < 640; i += 512) wlin_s[i] = Wlin[i];
    if (tid < 10) blin_s[tid] = blin[tid];
    __syncthreads();
    if (tid < 320) {
        int b = tid / 10, o = tid - b * 10;
        float a = blin_s[o];
        #pragma unroll 8
        for (int u = 0; u < 64; ++u) {
            float hv = (float)h1p[2048 + ((b >> 4) * 2 + (u >> 5)) * 512 + (((u >> 3) & 3) * 16 + (b & 15)) * 8 + (u & 7)];
            a += wlin_s[o * 64 + u] * hv;
        }
        out[(blockIdx.x * 32 + b) * 10 + o] = a;
    }
}

extern "C" void kernel_launch(void* const* d_in, const int* in_sizes, int n_in,
                              void* d_out, int out_size, void* d_ws, size_t ws_size,
                              hipStream_t stream) {
    const float* x    = (const float*)d_in[0];
    const float* Wih0 = (const float*)d_in[1];
    const float* Whh0 = (const float*)d_in[2];
    const float* bih0 = (const float*)d_in[3];
    const float* bhh0 = (const float*)d_in[4];
    const float* Wih1 = (const float*)d_in[5];
    const float* Whh1 = (const float*)d_in[6];
    const float* bih1 = (const float*)d_in[7];
    const float* bhh1 = (const float*)d_in[8];
    const float* Wlin = (const float*)d_in[9];
    const float* blin = (const float*)d_in[10];
    float* out = (float*)d_out;

    lstm_mfma<<<512, dim3(64, 8), 0, stream>>>(x, Wih0, Whh0, bih0, bhh0,
                                               Wih1, Whh1, bih1, bhh1, Wlin, blin, out);
}

// Round 9
// 195.291 us; speedup vs baseline: 1.1050x; 1.1050x over previous
//
#include <hip/hip_runtime.h>

// ------- MFMA fp16 LSTM, skewed-layer pipeline, 16 waves x 1 m-tile -------
// Round 9: round-5 control flow (best: 125us), but work split changed so true
// register pressure fits the allocator's stubborn 64-VGPR budget (4 rounds of
// occupancy hints never moved it): block = 1024 thr (16 waves), batch 32,
// wave w owns m-tile w (1 m-tile x 2 n-tiles). Per-wave A-frags 56->28 regs,
// acc 32->16, so nothing spills (rounds 3-8: 23-28 MB scratch writes killed
// the (.,4) configs). Weights pre-swizzled to fp16 frags by a prep kernel
// (clean dwordx4 A-loads, no gather temps).
//
// Phase p computes layer1(t=p) AND layer0(t=p+1) between barriers (29 total):
//   layer1(p)  reads h0(p), h1(p-1) -> writes h1(p)
//   layer0(p+1) reads x(p+1), h0(p) -> writes h0(p+1)   [shared h0 B-frags]
// GEMM: C[m=gate(256)][n=batch(32)] = W[m][k]*data[k][n]; gate rows permuted
// row'=4*unit+gate so a lane's 4 C-regs = (i,f,g,o) of unit u=4w+quad;
// c-state in VGPRs. bias0 folded as k=28 constant-1 column; bias1 in acc init.
// B in LDS frag-linear layout (lane reads 16B at lane*16, conflict-free b128).
// Planes: h0(t)->h0p[t&1], h1(t)->h1p[t&1], x(t)->xb[t&1].

typedef _Float16 half8 __attribute__((ext_vector_type(8)));
typedef float floatx4 __attribute__((ext_vector_type(4)));

#define NFRAG 112                   // 16 mt * 3 kt (L0) + 16 mt * 4 kt (L1)
#define WS_BIAS_OFF (NFRAG * 1024)  // bytes into d_ws for fp32 bias1[256]

__global__ void prep_kernel(const float* __restrict__ Wih0, const float* __restrict__ Whh0,
                            const float* __restrict__ bih0, const float* __restrict__ bhh0,
                            const float* __restrict__ Wih1, const float* __restrict__ Whh1,
                            const float* __restrict__ bih1, const float* __restrict__ bhh1,
                            _Float16* __restrict__ wA, float* __restrict__ wBias) {
    int idx = blockIdx.x * blockDim.x + threadIdx.x;
    if (idx < NFRAG * 512) {
        int f = idx >> 9, slot = idx & 511;
        int lane = slot >> 3, j = slot & 7;
        int mt, kt, layer;
        if (f < 48) { layer = 0; mt = f / 3; kt = f % 3; }
        else        { layer = 1; int f2 = f - 48; mt = f2 >> 2; kt = f2 & 3; }
        int m = mt * 16 + (lane & 15);          // permuted gate-row
        int k = kt * 32 + (lane >> 4) * 8 + j;  // A[m][k]: m=lane&15, k=quad*8+j
        int u = m >> 2, g = m & 3;
        int row = g * 64 + u;                    // original weight row
        float v;
        if (layer == 0) {
            if (k < 28)       v = Wih0[row * 28 + k];
            else if (k == 28) v = bih0[row] + bhh0[row];   // bias0 constant-1 col
            else if (k < 32)  v = 0.f;
            else              v = Whh0[row * 64 + (k - 32)];
        } else {
            if (k < 64)       v = Wih1[row * 64 + k];
            else              v = Whh1[row * 64 + (k - 64)];
        }
        wA[idx] = (_Float16)v;
    } else if (idx < NFRAG * 512 + 256) {
        int m = idx - NFRAG * 512;               // m = 4*unit + gate
        int row = (m & 3) * 64 + (m >> 2);
        wBias[m] = bih1[row] + bhh1[row];
    }
}

// Breadth-first N-tile gate batch: acc -> c update + h write (plane[i], offs[i]).
template <int N>
__device__ __forceinline__ void gate_batch(const floatx4* acc, float* c,
                                           _Float16* const* planes, const int* offs) {
    float ei[N], ef[N], eg[N], eo[N];
    #pragma unroll
    for (int i = 0; i < N; ++i) {
        floatx4 a = acc[i];
        ei[i] = __expf(-a[0]);
        ef[i] = __expf(-a[1]);
        eg[i] = __expf(2.0f * a[2]);
        eo[i] = __expf(-a[3]);
    }
    float ri[N], rf[N], rg[N], ro[N];
    #pragma unroll
    for (int i = 0; i < N; ++i) {
        ri[i] = __builtin_amdgcn_rcpf(1.0f + ei[i]);
        rf[i] = __builtin_amdgcn_rcpf(1.0f + ef[i]);
        rg[i] = __builtin_amdgcn_rcpf(1.0f + eg[i]);
        ro[i] = __builtin_amdgcn_rcpf(1.0f + eo[i]);
    }
    float ec[N];
    #pragma unroll
    for (int i = 0; i < N; ++i) {
        float tg = 1.0f - 2.0f * rg[i];
        float cn = rf[i] * c[i] + ri[i] * tg;
        c[i] = cn;
        ec[i] = __expf(2.0f * cn);
    }
    #pragma unroll
    for (int i = 0; i < N; ++i) {
        float tc = 1.0f - 2.0f * __builtin_amdgcn_rcpf(ec[i] + 1.0f);
        planes[i][offs[i]] = (_Float16)(ro[i] * tc);
    }
}

__launch_bounds__(1024, 4)
__global__ void lstm_mfma(const float* __restrict__ x,
                          const _Float16* __restrict__ wA,
                          const float* __restrict__ wBias,
                          const float* __restrict__ Wlin, const float* __restrict__ blin,
                          float* __restrict__ out) {
    __shared__ __align__(16) _Float16 h0p[2][2048];  // [parity][(nt*2+kt)*512 + lane*8 + j]
    __shared__ __align__(16) _Float16 h1p[2][2048];
    __shared__ __align__(16) _Float16 xb[2][1024];   // [parity][nt*512 + lane*8 + j]
    __shared__ float wlin_s[640];
    __shared__ float blin_s[10];

    const int lane = threadIdx.x;
    const int w    = threadIdx.y;          // 0..15 = m-tile
    const int tid  = w * 64 + lane;        // 0..1023
    const int quad = lane >> 4;
    const int col  = lane & 15;
    const int u    = 4 * w + quad;         // this lane's hidden unit

    // ---- A fragments: 7 clean dwordx4 loads/lane (28 VGPRs total) ----
    half8 A0[3], A1[4];
    #pragma unroll
    for (int kt = 0; kt < 3; ++kt)
        A0[kt] = *(const half8*)(wA + (w * 3 + kt) * 512 + lane * 8);
    #pragma unroll
    for (int kt = 0; kt < 4; ++kt)
        A1[kt] = *(const half8*)(wA + (48 + w * 4 + kt) * 512 + lane * 8);
    const floatx4 bias1 = *(const floatx4*)(wBias + u * 4);

    // ---- t-invariant LDS offsets (halves) ----
    int xrd[2], hrd[2][2], hwr[2];
    #pragma unroll
    for (int in = 0; in < 2; ++in) {
        xrd[in] = in * 512 + lane * 8;
        #pragma unroll
        for (int kt = 0; kt < 2; ++kt) hrd[kt][in] = (in * 2 + kt) * 512 + lane * 8;
        hwr[in] = (in * 2 + (u >> 5)) * 512 + (((u >> 3) & 3) * 16 + col) * 8 + (u & 7);
    }

    // ---- x staging: thread covers b=tid>>5 (0..31), i=tid&31 ----
    const int xi = tid & 31;
    const bool xvalid = xi < 28;
    const int xb_idx = tid >> 5;
    const float* xg = x + (blockIdx.x * 32 + xb_idx) * 784 + xi;
    const int xstg = (xb_idx >> 4) * 512 + ((xi >> 3) * 16 + (xb_idx & 15)) * 8 + (xi & 7);

    // ---- init: zero h0(-1)=h0p[1], h1(-1)=h1p[1]; stage x(0) -> xb[0] ----
    {
        ((int*)&h0p[1][0])[tid] = 0;
        ((int*)&h1p[1][0])[tid] = 0;
        float xv = xvalid ? xg[0] : 0.f;
        xb[0][xstg] = (xi == 28) ? (_Float16)1.0f : (_Float16)xv;
    }
    __syncthreads();

    float c0[2] = {0.f, 0.f};
    float c1[2] = {0.f, 0.f};

    for (int p = -1; p <= 27; ++p) {
        const int pr  = p & 1;              // note: -1 & 1 == 1 (h0(-1) zeros ✓)
        const int pr1 = pr ^ 1;
        const _Float16* h0r = h0p[pr];      // h0(p)
        _Float16*       h0w = h0p[pr1];     // h0(p+1)
        const _Float16* h1r = h1p[pr1];     // h1(p-1)
        _Float16*       h1w = h1p[pr];      // h1(p)
        const _Float16* xr  = xb[pr1];      // x(p+1)
        _Float16*       xw  = xb[pr];       // x(p+2) stage
        const bool doL0 = (p < 27);
        const bool doL1 = (p >= 0);

        // global prefetch x(p+2) (hidden under phase compute)
        float xn = 0.f;
        if (p <= 25 && xvalid) xn = xg[(p + 2) * 28];

        // shared h0(p) B-fragments
        half8 bh0[2][2];
        #pragma unroll
        for (int kt = 0; kt < 2; ++kt)
            #pragma unroll
            for (int in = 0; in < 2; ++in)
                bh0[kt][in] = *(const half8*)&h0r[hrd[kt][in]];

        floatx4 acc0[2], acc1[2];

        if (doL0) {                         // layer0(t=p+1)
            #pragma unroll
            for (int in = 0; in < 2; ++in) {
                half8 bf = *(const half8*)&xr[xrd[in]];
                acc0[in] = __builtin_amdgcn_mfma_f32_16x16x32_f16(
                               A0[0], bf, (floatx4){0.f, 0.f, 0.f, 0.f}, 0, 0, 0);
            }
            #pragma unroll
            for (int kt = 0; kt < 2; ++kt)
                #pragma unroll
                for (int in = 0; in < 2; ++in)
                    acc0[in] = __builtin_amdgcn_mfma_f32_16x16x32_f16(A0[kt + 1], bh0[kt][in], acc0[in], 0, 0, 0);
        }
        if (doL1) {                         // layer1(t=p)
            #pragma unroll
            for (int in = 0; in < 2; ++in) acc1[in] = bias1;
            #pragma unroll
            for (int kt = 0; kt < 2; ++kt)
                #pragma unroll
                for (int in = 0; in < 2; ++in)
                    acc1[in] = __builtin_amdgcn_mfma_f32_16x16x32_f16(A1[kt], bh0[kt][in], acc1[in], 0, 0, 0);
            #pragma unroll
            for (int kt = 0; kt < 2; ++kt)
                #pragma unroll
                for (int in = 0; in < 2; ++in) {
                    half8 bf = *(const half8*)&h1r[hrd[kt][in]];
                    acc1[in] = __builtin_amdgcn_mfma_f32_16x16x32_f16(A1[kt + 2], bf, acc1[in], 0, 0, 0);
                }
        }

        // gates: breadth-first over all live tiles
        if (doL0 && doL1) {
            floatx4 a4[4] = {acc0[0], acc0[1], acc1[0], acc1[1]};
            float   cc[4] = {c0[0], c0[1], c1[0], c1[1]};
            _Float16* pl[4] = {h0w, h0w, h1w, h1w};
            int offs[4] = {hwr[0], hwr[1], hwr[0], hwr[1]};
            gate_batch<4>(a4, cc, pl, offs);
            c0[0] = cc[0]; c0[1] = cc[1]; c1[0] = cc[2]; c1[1] = cc[3];
        } else if (doL0) {
            _Float16* pl[2] = {h0w, h0w};
            gate_batch<2>(acc0, c0, pl, hwr);
        } else {
            _Float16* pl[2] = {h1w, h1w};
            gate_batch<2>(acc1, c1, pl, hwr);
        }

        // stage x(p+2)
        if (p <= 25)
            xw[xstg] = (xi == 28) ? (_Float16)1.0f : (_Float16)xn;
        __syncthreads();    // h0(p+1), h1(p), x(p+2) visible
    }

    // ---- epilogue: out = h1(27) @ Wlin^T + blin   (h1(27) in h1p[1]) ----
    if (tid < 640) wlin_s[tid] = Wlin[tid];
    if (tid < 10)  blin_s[tid] = blin[tid];
    __syncthreads();
    if (tid < 320) {
        int b = tid / 10, o = tid - b * 10;
        float a = blin_s[o];
        #pragma unroll 8
        for (int uu = 0; uu < 64; ++uu) {
            float hv = (float)h1p[1][((b >> 4) * 2 + (uu >> 5)) * 512 + (((uu >> 3) & 3) * 16 + (b & 15)) * 8 + (uu & 7)];
            a += wlin_s[o * 64 + uu] * hv;
        }
        out[(blockIdx.x * 32 + b) * 10 + o] = a;
    }
}

extern "C" void kernel_launch(void* const* d_in, const int* in_sizes, int n_in,
                              void* d_out, int out_size, void* d_ws, size_t ws_size,
                              hipStream_t stream) {
    const float* x    = (const float*)d_in[0];
    const float* Wih0 = (const float*)d_in[1];
    const float* Whh0 = (const float*)d_in[2];
    const float* bih0 = (const float*)d_in[3];
    const float* bhh0 = (const float*)d_in[4];
    const float* Wih1 = (const float*)d_in[5];
    const float* Whh1 = (const float*)d_in[6];
    const float* bih1 = (const float*)d_in[7];
    const float* bhh1 = (const float*)d_in[8];
    const float* Wlin = (const float*)d_in[9];
    const float* blin = (const float*)d_in[10];
    float* out = (float*)d_out;

    _Float16* wA    = (_Float16*)d_ws;
    float*    wBias = (float*)((char*)d_ws + WS_BIAS_OFF);

    prep_kernel<<<225, 256, 0, stream>>>(Wih0, Whh0, bih0, bhh0,
                                         Wih1, Whh1, bih1, bhh1, wA, wBias);
    lstm_mfma<<<512, dim3(64, 16), 0, stream>>>(x, wA, wBias, Wlin, blin, out);
}

// Round 10
// 183.491 us; speedup vs baseline: 1.1761x; 1.0643x over previous
//
#include <hip/hip_runtime.h>

// --- MFMA fp16 LSTM, skewed-layer pipeline, 2 batch-groups/block, exp2 weights ---
// Round 10: (a) block processes TWO independent batch-32 groups per phase
// (grid 256 = 1 block/CU, single round; barriers per unit work halved; 2x ILP
// per inter-barrier region; A-frags amortized over 2x work). (b) prep kernel
// pre-scales gate rows by -log2e (i,f,o) / +2*log2e (g), so every activation
// exp is a bare v_exp_f32 (exp2) with no preceding multiply.
//
// Phase p per group: layer1(t=p) reads h0(p),h1(p-1); layer0(t=p+1) reads
// x(p+1),h0(p) [shared h0 B-frags]; 29 barriers total.
// GEMM: C[m=gate(256)][n=batch(32)] = W[m][k]*data[k][n]; gate rows permuted
// row'=4*unit+gate so a lane's 4 C-regs = (i,f,g,o) of unit u=4w+quad; c in VGPRs.
// Wave w owns m-tile w x 2 n-tiles (A-frags 28 regs -> fits the 64-VGPR budget
// the allocator insists on; r9 proved spill-free at VGPR 44 / WRITE 640 KB).
// B in LDS frag-linear layout (lane reads 16B at lane*16, conflict-free b128).
// Planes per group: h0(t)->h0p[G][t&1], h1(t)->h1p[G][t&1], x(t)->xb[G][t&1].

typedef _Float16 half8 __attribute__((ext_vector_type(8)));
typedef float floatx4 __attribute__((ext_vector_type(4)));

#define NFRAG 112                   // 16 mt * 3 kt (L0) + 16 mt * 4 kt (L1)
#define WS_BIAS_OFF (NFRAG * 1024)  // bytes into d_ws for fp32 bias1[256]
#define K2 2.8853900817779268f      // 2*log2(e)

#if __has_builtin(__builtin_amdgcn_exp2f)
#define EXP2(v) __builtin_amdgcn_exp2f(v)
#else
#define EXP2(v) __expf(0.6931471805599453f * (v))
#endif
#define RCP(v) __builtin_amdgcn_rcpf(v)

__global__ void prep_kernel(const float* __restrict__ Wih0, const float* __restrict__ Whh0,
                            const float* __restrict__ bih0, const float* __restrict__ bhh0,
                            const float* __restrict__ Wih1, const float* __restrict__ Whh1,
                            const float* __restrict__ bih1, const float* __restrict__ bhh1,
                            _Float16* __restrict__ wA, float* __restrict__ wBias) {
    int idx = blockIdx.x * blockDim.x + threadIdx.x;
    if (idx < NFRAG * 512) {
        int f = idx >> 9, slot = idx & 511;
        int lane = slot >> 3, j = slot & 7;
        int mt, kt, layer;
        if (f < 48) { layer = 0; mt = f / 3; kt = f % 3; }
        else        { layer = 1; int f2 = f - 48; mt = f2 >> 2; kt = f2 & 3; }
        int m = mt * 16 + (lane & 15);          // permuted gate-row: m = 4*unit + gate
        int k = kt * 32 + (lane >> 4) * 8 + j;  // A[m][k]: m=lane&15, k=quad*8+j
        int u = m >> 2, g = m & 3;
        int row = g * 64 + u;                    // original weight row
        float v;
        if (layer == 0) {
            if (k < 28)       v = Wih0[row * 28 + k];
            else if (k == 28) v = bih0[row] + bhh0[row];   // bias0 constant-1 col
            else if (k < 32)  v = 0.f;
            else              v = Whh0[row * 64 + (k - 32)];
        } else {
            if (k < 64)       v = Wih1[row * 64 + k];
            else              v = Whh1[row * 64 + (k - 64)];
        }
        // fold activation scaling into weights: exp(-a) / exp(2a) -> exp2(acc)
        float s = (g == 2) ? K2 : -1.4426950408889634f;
        wA[idx] = (_Float16)(v * s);
    } else if (idx < NFRAG * 512 + 256) {
        int m = idx - NFRAG * 512;               // m = 4*unit + gate
        int g = m & 3;
        int row = g * 64 + (m >> 2);
        float s = (g == 2) ? K2 : -1.4426950408889634f;
        wBias[m] = (bih1[row] + bhh1[row]) * s;
    }
}

// Breadth-first N-tile gate batch on PRE-SCALED accs:
// a[0]=-log2e*ai, a[1]=-log2e*af, a[2]=2log2e*ag, a[3]=-log2e*ao.
template <int N>
__device__ __forceinline__ void gate_batch(const floatx4* acc, float* c,
                                           _Float16* const* planes, const int* offs) {
    float ei[N], ef[N], eg[N], eo[N];
    #pragma unroll
    for (int i = 0; i < N; ++i) {
        floatx4 a = acc[i];
        ei[i] = EXP2(a[0]);     // e^{-ai}
        ef[i] = EXP2(a[1]);
        eg[i] = EXP2(a[2]);     // e^{2ag}
        eo[i] = EXP2(a[3]);
    }
    float ri[N], rf[N], rg[N], ro[N];
    #pragma unroll
    for (int i = 0; i < N; ++i) {
        ri[i] = RCP(1.0f + ei[i]);
        rf[i] = RCP(1.0f + ef[i]);
        rg[i] = RCP(1.0f + eg[i]);
        ro[i] = RCP(1.0f + eo[i]);
    }
    float ec[N];
    #pragma unroll
    for (int i = 0; i < N; ++i) {
        float tg = 1.0f - 2.0f * rg[i];
        float cn = rf[i] * c[i] + ri[i] * tg;
        c[i] = cn;
        ec[i] = EXP2(K2 * cn);  // e^{2c}
    }
    #pragma unroll
    for (int i = 0; i < N; ++i) {
        float tc = 1.0f - 2.0f * RCP(ec[i] + 1.0f);
        planes[i][offs[i]] = (_Float16)(ro[i] * tc);
    }
}

__launch_bounds__(1024, 4)
__global__ void lstm_mfma(const float* __restrict__ x,
                          const _Float16* __restrict__ wA,
                          const float* __restrict__ wBias,
                          const float* __restrict__ Wlin, const float* __restrict__ blin,
                          float* __restrict__ out) {
    __shared__ __align__(16) _Float16 h0p[2][2][2048];  // [group][parity][frag-linear]
    __shared__ __align__(16) _Float16 h1p[2][2][2048];
    __shared__ __align__(16) _Float16 xb[2][2][1024];
    __shared__ float wlin_s[640];
    __shared__ float blin_s[10];

    const int lane = threadIdx.x;
    const int w    = threadIdx.y;          // 0..15 = m-tile
    const int tid  = w * 64 + lane;        // 0..1023
    const int quad = lane >> 4;
    const int col  = lane & 15;
    const int u    = 4 * w + quad;         // this lane's hidden unit

    // ---- A fragments: 7 clean dwordx4 loads/lane (28 VGPRs), shared by both groups ----
    half8 A0[3], A1[4];
    #pragma unroll
    for (int kt = 0; kt < 3; ++kt)
        A0[kt] = *(const half8*)(wA + (w * 3 + kt) * 512 + lane * 8);
    #pragma unroll
    for (int kt = 0; kt < 4; ++kt)
        A1[kt] = *(const half8*)(wA + (48 + w * 4 + kt) * 512 + lane * 8);
    const floatx4 bias1 = *(const floatx4*)(wBias + u * 4);

    // ---- t-invariant LDS offsets (halves) ----
    int xrd[2], hrd[2][2], hwr[2];
    #pragma unroll
    for (int in = 0; in < 2; ++in) {
        xrd[in] = in * 512 + lane * 8;
        #pragma unroll
        for (int kt = 0; kt < 2; ++kt) hrd[kt][in] = (in * 2 + kt) * 512 + lane * 8;
        hwr[in] = (in * 2 + (u >> 5)) * 512 + (((u >> 3) & 3) * 16 + col) * 8 + (u & 7);
    }

    // ---- x staging: thread covers b=tid>>5 (0..31) of each group, i=tid&31 ----
    const int xi = tid & 31;
    const bool xvalid = xi < 28;
    const int xbi = tid >> 5;
    const float* xg = x + (blockIdx.x * 64 + xbi) * 784 + xi;   // group1 at +32*784
    const int xstg = (xbi >> 4) * 512 + ((xi >> 3) * 16 + (xbi & 15)) * 8 + (xi & 7);

    // ---- init: zero h0(-1),h1(-1) (parity 1) both groups; stage x(0) ----
    {
        ((int*)&h0p[0][1][0])[tid] = 0;
        ((int*)&h0p[1][1][0])[tid] = 0;
        ((int*)&h1p[0][1][0])[tid] = 0;
        ((int*)&h1p[1][1][0])[tid] = 0;
        float xv0 = xvalid ? xg[0] : 0.f;
        float xv1 = xvalid ? xg[32 * 784] : 0.f;
        xb[0][0][xstg] = (xi == 28) ? (_Float16)1.0f : (_Float16)xv0;
        xb[1][0][xstg] = (xi == 28) ? (_Float16)1.0f : (_Float16)xv1;
    }
    __syncthreads();

    float c0[2][2] = {{0.f, 0.f}, {0.f, 0.f}};
    float c1[2][2] = {{0.f, 0.f}, {0.f, 0.f}};

    for (int p = -1; p <= 27; ++p) {
        const int pr  = p & 1;              // -1&1==1: h0(-1)=zeros plane ✓
        const int pr1 = pr ^ 1;
        const bool doL0 = (p < 27);
        const bool doL1 = (p >= 0);

        // global prefetch x(p+2), both groups, issued first
        float xn[2] = {0.f, 0.f};
        if (p <= 25 && xvalid) {
            xn[0] = xg[(p + 2) * 28];
            xn[1] = xg[32 * 784 + (p + 2) * 28];
        }

        #pragma unroll
        for (int G = 0; G < 2; ++G) {
            const _Float16* h0r = h0p[G][pr];
            _Float16*       h0w = h0p[G][pr1];
            const _Float16* h1r = h1p[G][pr1];
            _Float16*       h1w = h1p[G][pr];
            const _Float16* xr  = xb[G][pr1];

            half8 bh0[2][2];
            #pragma unroll
            for (int kt = 0; kt < 2; ++kt)
                #pragma unroll
                for (int in = 0; in < 2; ++in)
                    bh0[kt][in] = *(const half8*)&h0r[hrd[kt][in]];

            floatx4 acc0[2], acc1[2];

            if (doL0) {                     // layer0(t=p+1)
                #pragma unroll
                for (int in = 0; in < 2; ++in) {
                    half8 bf = *(const half8*)&xr[xrd[in]];
                    acc0[in] = __builtin_amdgcn_mfma_f32_16x16x32_f16(
                                   A0[0], bf, (floatx4){0.f, 0.f, 0.f, 0.f}, 0, 0, 0);
                }
                #pragma unroll
                for (int kt = 0; kt < 2; ++kt)
                    #pragma unroll
                    for (int in = 0; in < 2; ++in)
                        acc0[in] = __builtin_amdgcn_mfma_f32_16x16x32_f16(A0[kt + 1], bh0[kt][in], acc0[in], 0, 0, 0);
            }
            if (doL1) {                     // layer1(t=p)
                #pragma unroll
                for (int in = 0; in < 2; ++in) acc1[in] = bias1;
                #pragma unroll
                for (int kt = 0; kt < 2; ++kt)
                    #pragma unroll
                    for (int in = 0; in < 2; ++in)
                        acc1[in] = __builtin_amdgcn_mfma_f32_16x16x32_f16(A1[kt], bh0[kt][in], acc1[in], 0, 0, 0);
                #pragma unroll
                for (int kt = 0; kt < 2; ++kt)
                    #pragma unroll
                    for (int in = 0; in < 2; ++in) {
                        half8 bf = *(const half8*)&h1r[hrd[kt][in]];
                        acc1[in] = __builtin_amdgcn_mfma_f32_16x16x32_f16(A1[kt + 2], bf, acc1[in], 0, 0, 0);
                    }
            }

            if (doL0 && doL1) {
                floatx4 a4[4] = {acc0[0], acc0[1], acc1[0], acc1[1]};
                float   cc[4] = {c0[G][0], c0[G][1], c1[G][0], c1[G][1]};
                _Float16* pl[4] = {h0w, h0w, h1w, h1w};
                int offs[4] = {hwr[0], hwr[1], hwr[0], hwr[1]};
                gate_batch<4>(a4, cc, pl, offs);
                c0[G][0] = cc[0]; c0[G][1] = cc[1]; c1[G][0] = cc[2]; c1[G][1] = cc[3];
            } else if (doL0) {
                _Float16* pl[2] = {h0w, h0w};
                gate_batch<2>(acc0, c0[G], pl, hwr);
            } else {
                _Float16* pl[2] = {h1w, h1w};
                gate_batch<2>(acc1, c1[G], pl, hwr);
            }

            if (p <= 25)
                xb[G][pr][xstg] = (xi == 28) ? (_Float16)1.0f : (_Float16)xn[G];
        }
        __syncthreads();    // h0(p+1), h1(p), x(p+2) visible, both groups
    }

    // ---- epilogue: out = h1(27) @ Wlin^T + blin   (h1(27) in parity-1 planes) ----
    if (tid < 640) wlin_s[tid] = Wlin[tid];
    if (tid < 10)  blin_s[tid] = blin[tid];
    __syncthreads();
    if (tid < 640) {
        int b = tid / 10, o = tid - b * 10;     // b = 0..63 local batch
        int G = b >> 5, bl = b & 31;
        float a = blin_s[o];
        #pragma unroll 8
        for (int uu = 0; uu < 64; ++uu) {
            float hv = (float)h1p[G][1][((bl >> 4) * 2 + (uu >> 5)) * 512 + (((uu >> 3) & 3) * 16 + (bl & 15)) * 8 + (uu & 7)];
            a += wlin_s[o * 64 + uu] * hv;
        }
        out[(blockIdx.x * 64 + b) * 10 + o] = a;
    }
}

extern "C" void kernel_launch(void* const* d_in, const int* in_sizes, int n_in,
                              void* d_out, int out_size, void* d_ws, size_t ws_size,
                              hipStream_t stream) {
    const float* x    = (const float*)d_in[0];
    const float* Wih0 = (const float*)d_in[1];
    const float* Whh0 = (const float*)d_in[2];
    const float* bih0 = (const float*)d_in[3];
    const float* bhh0 = (const float*)d_in[4];
    const float* Wih1 = (const float*)d_in[5];
    const float* Whh1 = (const float*)d_in[6];
    const float* bih1 = (const float*)d_in[7];
    const float* bhh1 = (const float*)d_in[8];
    const float* Wlin = (const float*)d_in[9];
    const float* blin = (const float*)d_in[10];
    float* out = (float*)d_out;

    _Float16* wA    = (_Float16*)d_ws;
    float*    wBias = (float*)((char*)d_ws + WS_BIAS_OFF);

    prep_kernel<<<225, 256, 0, stream>>>(Wih0, Whh0, bih0, bhh0,
                                         Wih1, Whh1, bih1, bhh1, wA, wBias);
    lstm_mfma<<<256, dim3(64, 16), 0, stream>>>(x, wA, wBias, Wlin, blin, out);
}

// Round 11
// 178.170 us; speedup vs baseline: 1.2112x; 1.0299x over previous
//
#include <hip/hip_runtime.h>

// --- MFMA fp16 LSTM, skewed pipeline, 2 groups/block, overlap-ordered phase ---
// Round 11: r10 structure, phase body reordered for pipe overlap:
//   x-prefetch -> ALL bx/bh0 ds_reads (both groups) -> L0+L1(h0) MFMAs ->
//   bh1 reads -> L1 tail MFMAs -> merged gate_batch<8> -> writes -> barrier.
// Rationale (r10 budget): VALU ~4.7k cyc/CU-phase (trans 2.5k), LDS pipe ~4.3k
// (16 waves x 20 b128 x 12cyc — inherent B-panel redundancy of the m-split),
// MFMA 2.2k; measured 8.7k/phase = ~50% overlap. Source order was serializing
// LDS vs gate-trans; this round interleaves them.
//
// Phase p per group: layer1(t=p) reads h0(p),h1(p-1); layer0(t=p+1) reads
// x(p+1),h0(p) [shared h0 B-frags]; 29 barriers.
// GEMM: C[m=gate(256)][n=batch(32)] = W[m][k]*data[k][n]; gate rows permuted
// row'=4*unit+gate -> lane's 4 C-regs = (i,f,g,o) of unit u=4w+quad; c in VGPRs.
// Wave w owns m-tile w x 2 n-tiles (A-frags 28 regs, fits 64-VGPR budget).
// Weights pre-scaled (prep): i/f/o rows by -log2e, g rows by +2log2e -> bare exp2.
// B in LDS frag-linear layout (lane reads 16B at lane*16, conflict-free b128).

typedef _Float16 half8 __attribute__((ext_vector_type(8)));
typedef float floatx4 __attribute__((ext_vector_type(4)));

#define NFRAG 112
#define WS_BIAS_OFF (NFRAG * 1024)
#define K2 2.8853900817779268f      // 2*log2(e)

#if __has_builtin(__builtin_amdgcn_exp2f)
#define EXP2(v) __builtin_amdgcn_exp2f(v)
#else
#define EXP2(v) __expf(0.6931471805599453f * (v))
#endif
#define RCP(v) __builtin_amdgcn_rcpf(v)

__global__ void prep_kernel(const float* __restrict__ Wih0, const float* __restrict__ Whh0,
                            const float* __restrict__ bih0, const float* __restrict__ bhh0,
                            const float* __restrict__ Wih1, const float* __restrict__ Whh1,
                            const float* __restrict__ bih1, const float* __restrict__ bhh1,
                            _Float16* __restrict__ wA, float* __restrict__ wBias) {
    int idx = blockIdx.x * blockDim.x + threadIdx.x;
    if (idx < NFRAG * 512) {
        int f = idx >> 9, slot = idx & 511;
        int lane = slot >> 3, j = slot & 7;
        int mt, kt, layer;
        if (f < 48) { layer = 0; mt = f / 3; kt = f % 3; }
        else        { layer = 1; int f2 = f - 48; mt = f2 >> 2; kt = f2 & 3; }
        int m = mt * 16 + (lane & 15);
        int k = kt * 32 + (lane >> 4) * 8 + j;
        int u = m >> 2, g = m & 3;
        int row = g * 64 + u;
        float v;
        if (layer == 0) {
            if (k < 28)       v = Wih0[row * 28 + k];
            else if (k == 28) v = bih0[row] + bhh0[row];
            else if (k < 32)  v = 0.f;
            else              v = Whh0[row * 64 + (k - 32)];
        } else {
            if (k < 64)       v = Wih1[row * 64 + k];
            else              v = Whh1[row * 64 + (k - 64)];
        }
        float s = (g == 2) ? K2 : -1.4426950408889634f;
        wA[idx] = (_Float16)(v * s);
    } else if (idx < NFRAG * 512 + 256) {
        int m = idx - NFRAG * 512;
        int g = m & 3;
        int row = g * 64 + (m >> 2);
        float s = (g == 2) ? K2 : -1.4426950408889634f;
        wBias[m] = (bih1[row] + bhh1[row]) * s;
    }
}

// Breadth-first N-tile gate batch on PRE-SCALED accs.
template <int N>
__device__ __forceinline__ void gate_batch(const floatx4* acc, float* c,
                                           _Float16* const* planes, const int* offs) {
    float ei[N], ef[N], eg[N], eo[N];
    #pragma unroll
    for (int i = 0; i < N; ++i) {
        floatx4 a = acc[i];
        ei[i] = EXP2(a[0]);
        ef[i] = EXP2(a[1]);
        eg[i] = EXP2(a[2]);
        eo[i] = EXP2(a[3]);
    }
    float ri[N], rf[N], rg[N], ro[N];
    #pragma unroll
    for (int i = 0; i < N; ++i) {
        ri[i] = RCP(1.0f + ei[i]);
        rf[i] = RCP(1.0f + ef[i]);
        rg[i] = RCP(1.0f + eg[i]);
        ro[i] = RCP(1.0f + eo[i]);
    }
    float ec[N];
    #pragma unroll
    for (int i = 0; i < N; ++i) {
        float tg = 1.0f - 2.0f * rg[i];
        float cn = rf[i] * c[i] + ri[i] * tg;
        c[i] = cn;
        ec[i] = EXP2(K2 * cn);
    }
    #pragma unroll
    for (int i = 0; i < N; ++i) {
        float tc = 1.0f - 2.0f * RCP(ec[i] + 1.0f);
        planes[i][offs[i]] = (_Float16)(ro[i] * tc);
    }
}

__launch_bounds__(1024, 4)
__global__ void lstm_mfma(const float* __restrict__ x,
                          const _Float16* __restrict__ wA,
                          const float* __restrict__ wBias,
                          const float* __restrict__ Wlin, const float* __restrict__ blin,
                          float* __restrict__ out) {
    __shared__ __align__(16) _Float16 h0p[2][2][2048];  // [group][parity][frag-linear]
    __shared__ __align__(16) _Float16 h1p[2][2][2048];
    __shared__ __align__(16) _Float16 xb[2][2][1024];
    __shared__ float wlin_s[640];
    __shared__ float blin_s[10];

    const int lane = threadIdx.x;
    const int w    = threadIdx.y;
    const int tid  = w * 64 + lane;
    const int quad = lane >> 4;
    const int col  = lane & 15;
    const int u    = 4 * w + quad;

    // ---- A fragments: 7 dwordx4 loads/lane, shared by both groups ----
    half8 A0[3], A1[4];
    #pragma unroll
    for (int kt = 0; kt < 3; ++kt)
        A0[kt] = *(const half8*)(wA + (w * 3 + kt) * 512 + lane * 8);
    #pragma unroll
    for (int kt = 0; kt < 4; ++kt)
        A1[kt] = *(const half8*)(wA + (48 + w * 4 + kt) * 512 + lane * 8);
    const floatx4 bias1 = *(const floatx4*)(wBias + u * 4);

    // ---- t-invariant LDS offsets (halves) ----
    int xrd[2], hrd[2][2], hwr[2];
    #pragma unroll
    for (int in = 0; in < 2; ++in) {
        xrd[in] = in * 512 + lane * 8;
        #pragma unroll
        for (int kt = 0; kt < 2; ++kt) hrd[kt][in] = (in * 2 + kt) * 512 + lane * 8;
        hwr[in] = (in * 2 + (u >> 5)) * 512 + (((u >> 3) & 3) * 16 + col) * 8 + (u & 7);
    }

    // ---- x staging: thread covers b=tid>>5 of each group, i=tid&31 ----
    const int xi = tid & 31;
    const bool xvalid = xi < 28;
    const int xbi = tid >> 5;
    const float* xg = x + (blockIdx.x * 64 + xbi) * 784 + xi;
    const int xstg = (xbi >> 4) * 512 + ((xi >> 3) * 16 + (xbi & 15)) * 8 + (xi & 7);

    // ---- init ----
    {
        ((int*)&h0p[0][1][0])[tid] = 0;
        ((int*)&h0p[1][1][0])[tid] = 0;
        ((int*)&h1p[0][1][0])[tid] = 0;
        ((int*)&h1p[1][1][0])[tid] = 0;
        float xv0 = xvalid ? xg[0] : 0.f;
        float xv1 = xvalid ? xg[32 * 784] : 0.f;
        xb[0][0][xstg] = (xi == 28) ? (_Float16)1.0f : (_Float16)xv0;
        xb[1][0][xstg] = (xi == 28) ? (_Float16)1.0f : (_Float16)xv1;
    }
    __syncthreads();

    float c0[2][2] = {{0.f, 0.f}, {0.f, 0.f}};
    float c1[2][2] = {{0.f, 0.f}, {0.f, 0.f}};

    for (int p = -1; p <= 27; ++p) {
        const int pr  = p & 1;
        const int pr1 = pr ^ 1;
        const bool doL0 = (p < 27);
        const bool doL1 = (p >= 0);

        // (1) global prefetch x(p+2), both groups, first in the phase
        float xn[2] = {0.f, 0.f};
        if (p <= 25 && xvalid) {
            xn[0] = xg[(p + 2) * 28];
            xn[1] = xg[32 * 784 + (p + 2) * 28];
        }

        // (2) up-front B-frag reads for BOTH groups: bx + bh0 (12 b128)
        half8 bx[2][2], bh0[2][2][2];
        if (doL0) {
            #pragma unroll
            for (int G = 0; G < 2; ++G)
                #pragma unroll
                for (int in = 0; in < 2; ++in)
                    bx[G][in] = *(const half8*)&xb[G][pr1][xrd[in]];
        }
        #pragma unroll
        for (int G = 0; G < 2; ++G)
            #pragma unroll
            for (int kt = 0; kt < 2; ++kt)
                #pragma unroll
                for (int in = 0; in < 2; ++in)
                    bh0[G][kt][in] = *(const half8*)&h0p[G][pr][hrd[kt][in]];

        // (3) L0 MFMAs + L1 h0-part MFMAs (consume bx, bh0)
        floatx4 acc0[2][2], acc1[2][2];
        if (doL0) {
            #pragma unroll
            for (int G = 0; G < 2; ++G)
                #pragma unroll
                for (int in = 0; in < 2; ++in) {
                    acc0[G][in] = __builtin_amdgcn_mfma_f32_16x16x32_f16(
                                      A0[0], bx[G][in], (floatx4){0.f, 0.f, 0.f, 0.f}, 0, 0, 0);
                    #pragma unroll
                    for (int kt = 0; kt < 2; ++kt)
                        acc0[G][in] = __builtin_amdgcn_mfma_f32_16x16x32_f16(
                                          A0[kt + 1], bh0[G][kt][in], acc0[G][in], 0, 0, 0);
                }
        }
        if (doL1) {
            #pragma unroll
            for (int G = 0; G < 2; ++G)
                #pragma unroll
                for (int in = 0; in < 2; ++in) {
                    acc1[G][in] = bias1;
                    #pragma unroll
                    for (int kt = 0; kt < 2; ++kt)
                        acc1[G][in] = __builtin_amdgcn_mfma_f32_16x16x32_f16(
                                          A1[kt], bh0[G][kt][in], acc1[G][in], 0, 0, 0);
                }

            // (4) bh1 reads then L1 tail MFMAs
            half8 bh1[2][2][2];
            #pragma unroll
            for (int G = 0; G < 2; ++G)
                #pragma unroll
                for (int kt = 0; kt < 2; ++kt)
                    #pragma unroll
                    for (int in = 0; in < 2; ++in)
                        bh1[G][kt][in] = *(const half8*)&h1p[G][pr1][hrd[kt][in]];
            #pragma unroll
            for (int G = 0; G < 2; ++G)
                #pragma unroll
                for (int kt = 0; kt < 2; ++kt)
                    #pragma unroll
                    for (int in = 0; in < 2; ++in)
                        acc1[G][in] = __builtin_amdgcn_mfma_f32_16x16x32_f16(
                                          A1[kt + 2], bh1[G][kt][in], acc1[G][in], 0, 0, 0);
        }

        // (5) gates: one merged breadth-first batch across both groups
        if (doL0 && doL1) {
            floatx4 a8[8] = {acc0[0][0], acc0[0][1], acc1[0][0], acc1[0][1],
                             acc0[1][0], acc0[1][1], acc1[1][0], acc1[1][1]};
            float   cc[8] = {c0[0][0], c0[0][1], c1[0][0], c1[0][1],
                             c0[1][0], c0[1][1], c1[1][0], c1[1][1]};
            _Float16* pl[8] = {h0p[0][pr1], h0p[0][pr1], h1p[0][pr], h1p[0][pr],
                               h0p[1][pr1], h0p[1][pr1], h1p[1][pr], h1p[1][pr]};
            int offs[8] = {hwr[0], hwr[1], hwr[0], hwr[1],
                           hwr[0], hwr[1], hwr[0], hwr[1]};
            gate_batch<8>(a8, cc, pl, offs);
            c0[0][0] = cc[0]; c0[0][1] = cc[1]; c1[0][0] = cc[2]; c1[0][1] = cc[3];
            c0[1][0] = cc[4]; c0[1][1] = cc[5]; c1[1][0] = cc[6]; c1[1][1] = cc[7];
        } else if (doL0) {
            floatx4 a4[4] = {acc0[0][0], acc0[0][1], acc0[1][0], acc0[1][1]};
            float   cc[4] = {c0[0][0], c0[0][1], c0[1][0], c0[1][1]};
            _Float16* pl[4] = {h0p[0][pr1], h0p[0][pr1], h0p[1][pr1], h0p[1][pr1]};
            int offs[4] = {hwr[0], hwr[1], hwr[0], hwr[1]};
            gate_batch<4>(a4, cc, pl, offs);
            c0[0][0] = cc[0]; c0[0][1] = cc[1]; c0[1][0] = cc[2]; c0[1][1] = cc[3];
        } else {
            floatx4 a4[4] = {acc1[0][0], acc1[0][1], acc1[1][0], acc1[1][1]};
            float   cc[4] = {c1[0][0], c1[0][1], c1[1][0], c1[1][1]};
            _Float16* pl[4] = {h1p[0][pr], h1p[0][pr], h1p[1][pr], h1p[1][pr]};
            int offs[4] = {hwr[0], hwr[1], hwr[0], hwr[1]};
            gate_batch<4>(a4, cc, pl, offs);
            c1[0][0] = cc[0]; c1[0][1] = cc[1]; c1[1][0] = cc[2]; c1[1][1] = cc[3];
        }

        // (6) x staging, then barrier
        if (p <= 25) {
            xb[0][pr][xstg] = (xi == 28) ? (_Float16)1.0f : (_Float16)xn[0];
            xb[1][pr][xstg] = (xi == 28) ? (_Float16)1.0f : (_Float16)xn[1];
        }
        __syncthreads();
    }

    // ---- epilogue: out = h1(27) @ Wlin^T + blin ----
    if (tid < 640) wlin_s[tid] = Wlin[tid];
    if (tid < 10)  blin_s[tid] = blin[tid];
    __syncthreads();
    if (tid < 640) {
        int b = tid / 10, o = tid - b * 10;
        int G = b >> 5, bl = b & 31;
        float a = blin_s[o];
        #pragma unroll 8
        for (int uu = 0; uu < 64; ++uu) {
            float hv = (float)h1p[G][1][((bl >> 4) * 2 + (uu >> 5)) * 512 + (((uu >> 3) & 3) * 16 + (bl & 15)) * 8 + (uu & 7)];
            a += wlin_s[o * 64 + uu] * hv;
        }
        out[(blockIdx.x * 64 + b) * 10 + o] = a;
    }
}

extern "C" void kernel_launch(void* const* d_in, const int* in_sizes, int n_in,
                              void* d_out, int out_size, void* d_ws, size_t ws_size,
                              hipStream_t stream) {
    const float* x    = (const float*)d_in[0];
    const float* Wih0 = (const float*)d_in[1];
    const float* Whh0 = (const float*)d_in[2];
    const float* bih0 = (const float*)d_in[3];
    const float* bhh0 = (const float*)d_in[4];
    const float* Wih1 = (const float*)d_in[5];
    const float* Whh1 = (const float*)d_in[6];
    const float* bih1 = (const float*)d_in[7];
    const float* bhh1 = (const float*)d_in[8];
    const float* Wlin = (const float*)d_in[9];
    const float* blin = (const float*)d_in[10];
    float* out = (float*)d_out;

    _Float16* wA    = (_Float16*)d_ws;
    float*    wBias = (float*)((char*)d_ws + WS_BIAS_OFF);

    prep_kernel<<<225, 256, 0, stream>>>(Wih0, Whh0, bih0, bhh0,
                                         Wih1, Whh1, bih1, bhh1, wA, wBias);
    lstm_mfma<<<256, dim3(64, 16), 0, stream>>>(x, wA, wBias, Wlin, blin, out);
}